// Round 2
// baseline (835.612 us; speedup 1.0000x reference)
//
#include <hip/hip_runtime.h>
#include <hip/hip_bf16.h>

// ---------------------------------------------------------------------------
// LossNet: x (12288,128) fp32 -> scalar loss.  bsz=4096.
// Reduced task set (zx/zy folded into colsums of xz/yz; xx/yy symmetric):
//   task 0 xx (sym), 1 yy (sym), 2 xy, 3 xz (+colsum->slot5), 4 yz (+colsum->slot6)
// rowsum slots: 0 s_xx, 1 s_yy, 2 s_xy, 3 s_ax, 4 s_ay, 5 s_zx, 6 s_zy
// diag  slots: 0..4 (d_zx = diag3, d_zy = diag4)
// ---------------------------------------------------------------------------

typedef __attribute__((ext_vector_type(8))) short short8;   // 8 x bf16
typedef __attribute__((ext_vector_type(4))) float floatx4;  // MFMA acc

#define D      128
#define BM     128   // rows per block
#define BN     64    // cols per j-tile
#define BPAD   136   // LDS row stride in shorts (2-way alias = free)
#define NROWB  32    // bsz/BM
#define NJT    64    // bsz/BN

// grid layout (chunk = 2 j-tiles):
//   xx: [0,528)  yy: [528,1056)  xy: [1056,2080)  xz: [2080,3104)  yz: [3104,4128)
#define GRID_EXPSIM 4128

#define LDAGENT(p) __hip_atomic_load(&(p), __ATOMIC_RELAXED, __HIP_MEMORY_SCOPE_AGENT)

// ---------------------------------------------------------------------------
// Kernel 1: row-normalize fp32 -> bf16, prescaled by sqrt(10) so that
// dot(a,b) = 10*cos(a,b).  Also zeroes rowsum[7][4096] and the ticket counter.
// ---------------------------------------------------------------------------
__global__ __launch_bounds__(256) void normalize_kernel(
    const float* __restrict__ x, short* __restrict__ xn,
    float* __restrict__ rowsum, int* __restrict__ counter, int rows) {
  int tid = threadIdx.x;
  if (blockIdx.x < 112) rowsum[blockIdx.x * 256 + tid] = 0.0f;  // 112*256 = 7*4096
  if (blockIdx.x == 0 && tid == 0) *counter = 0;

  int row  = blockIdx.x * 4 + (tid >> 6);
  int lane = tid & 63;
  if (row >= rows) return;
  const float2* xr = (const float2*)(x + (size_t)row * D);
  float2 v = xr[lane];
  float s = v.x * v.x + v.y * v.y;
#pragma unroll
  for (int off = 1; off < 64; off <<= 1) s += __shfl_xor(s, off, 64);
  float scale = 3.1622776601683795f / fmaxf(sqrtf(s), 1e-12f);  // sqrt(10)/||x||
  __hip_bfloat162 h;
  h.x = __float2bfloat16(v.x * scale);
  h.y = __float2bfloat16(v.y * scale);
  ((__hip_bfloat162*)xn)[(size_t)row * 64 + lane] = h;
}

// ---------------------------------------------------------------------------
// Epilogue: exp, rowsum partials, optional colsum partials + flush, optional diag.
// C/D layout: col = lm, row = quad*4 + reg  [m89-verified]
// ---------------------------------------------------------------------------
template <bool COL, bool DIAG>
__device__ __forceinline__ void epilogue(
    const floatx4 (&acc)[2][4], float (&rs)[2][4], int rowg0, int colg0,
    int quad, int lm, float* __restrict__ colsum_ptr, float* __restrict__ diag_ptr) {
  float cs[4] = {0.f, 0.f, 0.f, 0.f};
#pragma unroll
  for (int mi = 0; mi < 2; mi++) {
#pragma unroll
    for (int r = 0; r < 4; r++) {
      int rowg = rowg0 + mi * 16 + quad * 4 + r;
      float part = 0.f;
#pragma unroll
      for (int ni = 0; ni < 4; ni++) {
        float e = __expf(acc[mi][ni][r]);   // acc already = 10*cos
        part += e;
        if (COL) cs[ni] += e;
        if (DIAG) {
          if (colg0 + ni * 16 + lm == rowg) diag_ptr[rowg] = e;
        }
      }
      rs[mi][r] += part;
    }
  }
  if (COL) {
#pragma unroll
    for (int ni = 0; ni < 4; ni++) {
      float v = cs[ni];
      v += __shfl_xor(v, 16, 64);
      v += __shfl_xor(v, 32, 64);
      if (quad == 0) atomicAdd(&colsum_ptr[colg0 + ni * 16 + lm], v);
    }
  }
}

// ---------------------------------------------------------------------------
// Kernel 2: fused exp-sim + (last block) loss reduction.
// ---------------------------------------------------------------------------
__global__ __launch_bounds__(256, 6) void expsim_kernel(
    const short* __restrict__ xn, float* __restrict__ rowsum,
    float* __restrict__ diag, int* __restrict__ counter,
    float* __restrict__ out, int bsz) {
  __shared__ short ldsB[BN * BPAD];
  __shared__ float red[256];
  __shared__ int amLast;

  int tid = threadIdx.x;

  // ---- block -> (task, iblk, chunk) decode ----
  int bx = blockIdx.x;
  int task, iblk, chunk;
  if (bx < 1056) {            // symmetric tasks: chunks per iblk = 32 - iblk
    int local = bx;
    task = 0;
    if (local >= 528) { task = 1; local -= 528; }
    int i = 0;
    while (local >= 32 - i) { local -= 32 - i; i++; }
    iblk = i; chunk = local;
  } else {                    // full tasks: 32 chunks per iblk
    int local = bx - 1056;
    task = 2 + (local >> 10);
    local &= 1023;
    iblk = local >> 5;
    chunk = local & 31;
  }
  int jt0;
  bool dg, cen;
  if (task < 2) { jt0 = 2 * iblk + 2 * chunk; dg = (chunk == 0); cen = (chunk != 0); }
  else          { jt0 = 2 * chunk;            dg = (chunk == iblk); cen = (task >= 3); }

  int aoff = (task == 1 || task == 4) ? 1 : 0;
  int boff = (task < 2) ? task : ((task == 2) ? 1 : 2);
  int cslot = (task < 2) ? task : task + 2;   // 0,1,-,5,6

  int arow0     = aoff * bsz + iblk * BM;
  int brow_base = boff * bsz;

  int w    = tid >> 6;     // wave: rows w*32..w*32+31
  int lane = tid & 63;
  int quad = lane >> 4;
  int lm   = lane & 15;
  int rowg0 = iblk * BM + w * 32;

  float* colsum_ptr = rowsum + cslot * bsz;
  float* diag_ptr   = diag + task * bsz;

  // ---- A fragments, resident for whole block ----
  short8 afrag[2][4];
#pragma unroll
  for (int mi = 0; mi < 2; mi++) {
    int r = arow0 + w * 32 + mi * 16 + lm;
    const short8* ap = (const short8*)(xn + (size_t)r * D);
#pragma unroll
    for (int kk = 0; kk < 4; kk++) afrag[mi][kk] = ap[kk * 4 + quad];
  }

  float rs[2][4];
#pragma unroll
  for (int mi = 0; mi < 2; mi++)
#pragma unroll
    for (int r = 0; r < 4; r++) rs[mi][r] = 0.0f;

  // ---- 2 j-tiles per block ----
  for (int t = 0; t < 2; t++) {
    int jt    = jt0 + t;
    int colg0 = jt * BN;
    __syncthreads();
    const short* bsrc = xn + ((size_t)brow_base + colg0) * D;
#pragma unroll
    for (int it = 0; it < 4; it++) {
      int c = it * 256 + tid;
      int br = c >> 4, c16 = c & 15;
      *(short8*)(&ldsB[br * BPAD + c16 * 8]) =
          *(const short8*)(bsrc + (size_t)br * D + c16 * 8);
    }
    __syncthreads();

    floatx4 acc[2][4];
#pragma unroll
    for (int mi = 0; mi < 2; mi++)
#pragma unroll
      for (int ni = 0; ni < 4; ni++) acc[mi][ni] = (floatx4){0.f, 0.f, 0.f, 0.f};

#pragma unroll
    for (int kk = 0; kk < 4; kk++) {
      short8 bfrag[4];
#pragma unroll
      for (int ni = 0; ni < 4; ni++)
        bfrag[ni] = *(const short8*)(&ldsB[(ni * 16 + lm) * BPAD + kk * 32 + quad * 8]);
#pragma unroll
      for (int mi = 0; mi < 2; mi++)
#pragma unroll
        for (int ni = 0; ni < 4; ni++)
          acc[mi][ni] = __builtin_amdgcn_mfma_f32_16x16x32_bf16(
              afrag[mi][kk], bfrag[ni], acc[mi][ni], 0, 0, 0);
    }

    if (dg) {
      if (cen) epilogue<true, true>(acc, rs, rowg0, colg0, quad, lm, colsum_ptr, diag_ptr);
      else     epilogue<false, true>(acc, rs, rowg0, colg0, quad, lm, colsum_ptr, diag_ptr);
    } else {
      if (cen) epilogue<true, false>(acc, rs, rowg0, colg0, quad, lm, colsum_ptr, diag_ptr);
      else     epilogue<false, false>(acc, rs, rowg0, colg0, quad, lm, colsum_ptr, diag_ptr);
    }
  }

  // ---- row-sum flush: reduce over lm within quad, one atomic per row ----
#pragma unroll
  for (int mi = 0; mi < 2; mi++) {
#pragma unroll
    for (int r = 0; r < 4; r++) {
      float v = rs[mi][r];
      v += __shfl_xor(v, 1, 64);
      v += __shfl_xor(v, 2, 64);
      v += __shfl_xor(v, 4, 64);
      v += __shfl_xor(v, 8, 64);
      if (lm == 0)
        atomicAdd(&rowsum[task * bsz + rowg0 + mi * 16 + quad * 4 + r], v);
    }
  }

  // ---- last-block loss reduction (decoupled-lookback style) ----
  __threadfence();
  __syncthreads();
  if (tid == 0) {
    int t = __hip_atomic_fetch_add(counter, 1, __ATOMIC_ACQ_REL,
                                   __HIP_MEMORY_SCOPE_AGENT);
    amLast = (t == (int)gridDim.x - 1);
  }
  __syncthreads();
  if (amLast) {
    __threadfence();
    float accv = 0.0f;
    for (int i = tid; i < bsz; i += 256) {
      float s_xx = LDAGENT(rowsum[0 * bsz + i]), d_xx = LDAGENT(diag[0 * bsz + i]);
      float s_yy = LDAGENT(rowsum[1 * bsz + i]), d_yy = LDAGENT(diag[1 * bsz + i]);
      float s_xy = LDAGENT(rowsum[2 * bsz + i]), d_xy = LDAGENT(diag[2 * bsz + i]);
      float s_ax = LDAGENT(rowsum[3 * bsz + i]), d_ax = LDAGENT(diag[3 * bsz + i]);
      float s_ay = LDAGENT(rowsum[4 * bsz + i]), d_ay = LDAGENT(diag[4 * bsz + i]);
      float s_zx = LDAGENT(rowsum[5 * bsz + i]), d_zx = d_ax;
      float s_zy = LDAGENT(rowsum[6 * bsz + i]), d_zy = d_ay;
      float denom = (s_xy - d_xy) + (s_xx - d_xx) + (s_yy - d_yy);
      float tloc = -2.0f * __logf(d_xy / denom);
      tloc -= __logf(d_ax / (s_ax - d_ax));
      tloc -= __logf(d_ay / (s_ay - d_ay));
      tloc -= __logf(d_zx / (s_zx - d_zx));
      tloc -= __logf(d_zy / (s_zy - d_zy));
      accv += tloc;
    }
    red[tid] = accv;
    __syncthreads();
    for (int s = 128; s > 0; s >>= 1) {
      if (tid < s) red[tid] += red[tid + s];
      __syncthreads();
    }
    if (tid == 0) out[0] = red[0] / (float)bsz;
  }
}

// ---------------------------------------------------------------------------
extern "C" void kernel_launch(void* const* d_in, const int* in_sizes, int n_in,
                              void* d_out, int out_size, void* d_ws, size_t ws_size,
                              hipStream_t stream) {
  const float* x = (const float*)d_in[0];
  int rows = in_sizes[0] / D;   // 12288
  int bsz  = rows / 3;          // 4096

  char*  ws       = (char*)d_ws;
  short* xn       = (short*)ws;                        // rows*D bf16
  size_t xn_bytes = (size_t)rows * D * sizeof(short);  // 3 MiB
  float* rowsum   = (float*)(ws + xn_bytes);           // [7][bsz]
  float* dg       = rowsum + 7 * bsz;                  // [5][bsz]
  int*   counter  = (int*)(dg + 5 * bsz);

  normalize_kernel<<<rows / 4, 256, 0, stream>>>(x, xn, rowsum, counter, rows);
  expsim_kernel<<<GRID_EXPSIM, 256, 0, stream>>>(xn, rowsum, dg, counter,
                                                 (float*)d_out, bsz);
}

// Round 3
// 396.013 us; speedup vs baseline: 2.1101x; 2.1101x over previous
//
#include <hip/hip_runtime.h>
#include <hip/hip_bf16.h>

// ---------------------------------------------------------------------------
// LossNet: x (12288,128) fp32 -> scalar loss.  bsz=4096.
// Reduced task set (zx/zy folded into colsums of xz/yz; xx/yy symmetric):
//   task 0 xx (sym), 1 yy (sym), 2 xy, 3 xz (+colsum->slot5), 4 yz (+colsum->slot6)
// rowsum slots: 0 s_xx, 1 s_yy, 2 s_xy, 3 s_ax, 4 s_ay, 5 s_zx, 6 s_zy
// diag  slots: 0..4 (d_zx = diag3, d_zy = diag4)
// ---------------------------------------------------------------------------

typedef __attribute__((ext_vector_type(8))) short short8;   // 8 x bf16
typedef __attribute__((ext_vector_type(4))) float floatx4;  // MFMA acc

#define D      128
#define BM     128   // rows per block
#define BN     64    // cols per j-tile
#define BPAD   136   // LDS row stride in shorts (2-way alias = free)

// grid layout (chunk = 2 j-tiles):
//   xx: [0,528)  yy: [528,1056)  xy: [1056,2080)  xz: [2080,3104)  yz: [3104,4128)
#define GRID_EXPSIM 4128

#define LDAGENT(p) __hip_atomic_load(&(p), __ATOMIC_RELAXED, __HIP_MEMORY_SCOPE_AGENT)

// ---------------------------------------------------------------------------
// Kernel 1: row-normalize fp32 -> bf16, prescaled by sqrt(10) so that
// dot(a,b) = 10*cos(a,b).  Also zeroes rowsum[7][4096] and the ticket counter.
// ---------------------------------------------------------------------------
__global__ __launch_bounds__(256) void normalize_kernel(
    const float* __restrict__ x, short* __restrict__ xn,
    float* __restrict__ rowsum, int* __restrict__ counter, int rows) {
  int tid = threadIdx.x;
  if (blockIdx.x < 112) rowsum[blockIdx.x * 256 + tid] = 0.0f;  // 112*256 = 7*4096
  if (blockIdx.x == 0 && tid == 0) *counter = 0;

  int row  = blockIdx.x * 4 + (tid >> 6);
  int lane = tid & 63;
  if (row >= rows) return;
  const float2* xr = (const float2*)(x + (size_t)row * D);
  float2 v = xr[lane];
  float s = v.x * v.x + v.y * v.y;
#pragma unroll
  for (int off = 1; off < 64; off <<= 1) s += __shfl_xor(s, off, 64);
  float scale = 3.1622776601683795f / fmaxf(sqrtf(s), 1e-12f);  // sqrt(10)/||x||
  __hip_bfloat162 h;
  h.x = __float2bfloat16(v.x * scale);
  h.y = __float2bfloat16(v.y * scale);
  ((__hip_bfloat162*)xn)[(size_t)row * 64 + lane] = h;
}

// ---------------------------------------------------------------------------
// Epilogue: exp, rowsum partials, optional colsum partials + flush, optional diag.
// C/D layout: col = lm, row = quad*4 + reg  [m89-verified]
// ---------------------------------------------------------------------------
template <bool COL, bool DIAG>
__device__ __forceinline__ void epilogue(
    const floatx4 (&acc)[2][4], float (&rs)[2][4], int rowg0, int colg0,
    int quad, int lm, float* __restrict__ colsum_ptr, float* __restrict__ diag_ptr) {
  float cs[4] = {0.f, 0.f, 0.f, 0.f};
#pragma unroll
  for (int mi = 0; mi < 2; mi++) {
#pragma unroll
    for (int r = 0; r < 4; r++) {
      int rowg = rowg0 + mi * 16 + quad * 4 + r;
      float part = 0.f;
#pragma unroll
      for (int ni = 0; ni < 4; ni++) {
        float e = __expf(acc[mi][ni][r]);   // acc already = 10*cos
        part += e;
        if (COL) cs[ni] += e;
        if (DIAG) {
          if (colg0 + ni * 16 + lm == rowg) diag_ptr[rowg] = e;
        }
      }
      rs[mi][r] += part;
    }
  }
  if (COL) {
#pragma unroll
    for (int ni = 0; ni < 4; ni++) {
      float v = cs[ni];
      v += __shfl_xor(v, 16, 64);
      v += __shfl_xor(v, 32, 64);
      if (quad == 0) atomicAdd(&colsum_ptr[colg0 + ni * 16 + lm], v);
    }
  }
}

// ---------------------------------------------------------------------------
// Kernel 2: fused exp-sim + (last block) loss reduction.
// NOTE: plain __launch_bounds__(256) — forcing min-waves (e.g. ",6") caps
// VGPRs below the ~110 live range and spills acc/frags to scratch
// (R2: 450 MB HBM scratch traffic, 13x regression).
// ---------------------------------------------------------------------------
__global__ __launch_bounds__(256) void expsim_kernel(
    const short* __restrict__ xn, float* __restrict__ rowsum,
    float* __restrict__ diag, int* __restrict__ counter,
    float* __restrict__ out, int bsz) {
  __shared__ short ldsB[BN * BPAD];
  __shared__ float red[256];
  __shared__ int amLast;

  int tid = threadIdx.x;

  // ---- block -> (task, iblk, chunk) decode ----
  int bx = blockIdx.x;
  int task, iblk, chunk;
  if (bx < 1056) {            // symmetric tasks: chunks per iblk = 32 - iblk
    int local = bx;
    task = 0;
    if (local >= 528) { task = 1; local -= 528; }
    int i = 0;
    while (local >= 32 - i) { local -= 32 - i; i++; }
    iblk = i; chunk = local;
  } else {                    // full tasks: 32 chunks per iblk
    int local = bx - 1056;
    task = 2 + (local >> 10);
    local &= 1023;
    iblk = local >> 5;
    chunk = local & 31;
  }
  int jt0;
  bool dg, cen;
  if (task < 2) { jt0 = 2 * iblk + 2 * chunk; dg = (chunk == 0); cen = (chunk != 0); }
  else          { jt0 = 2 * chunk;            dg = (chunk == iblk); cen = (task >= 3); }

  int aoff = (task == 1 || task == 4) ? 1 : 0;
  int boff = (task < 2) ? task : ((task == 2) ? 1 : 2);
  int cslot = (task < 2) ? task : task + 2;   // 0,1,-,5,6

  int arow0     = aoff * bsz + iblk * BM;
  int brow_base = boff * bsz;

  int w    = tid >> 6;     // wave: rows w*32..w*32+31
  int lane = tid & 63;
  int quad = lane >> 4;
  int lm   = lane & 15;
  int rowg0 = iblk * BM + w * 32;

  float* colsum_ptr = rowsum + cslot * bsz;
  float* diag_ptr   = diag + task * bsz;

  // ---- A fragments, resident for whole block ----
  short8 afrag[2][4];
#pragma unroll
  for (int mi = 0; mi < 2; mi++) {
    int r = arow0 + w * 32 + mi * 16 + lm;
    const short8* ap = (const short8*)(xn + (size_t)r * D);
#pragma unroll
    for (int kk = 0; kk < 4; kk++) afrag[mi][kk] = ap[kk * 4 + quad];
  }

  float rs[2][4];
#pragma unroll
  for (int mi = 0; mi < 2; mi++)
#pragma unroll
    for (int r = 0; r < 4; r++) rs[mi][r] = 0.0f;

  // ---- 2 j-tiles per block ----
  for (int t = 0; t < 2; t++) {
    int jt    = jt0 + t;
    int colg0 = jt * BN;
    __syncthreads();
    const short* bsrc = xn + ((size_t)brow_base + colg0) * D;
#pragma unroll
    for (int it = 0; it < 4; it++) {
      int c = it * 256 + tid;
      int br = c >> 4, c16 = c & 15;
      *(short8*)(&ldsB[br * BPAD + c16 * 8]) =
          *(const short8*)(bsrc + (size_t)br * D + c16 * 8);
    }
    __syncthreads();

    floatx4 acc[2][4];
#pragma unroll
    for (int mi = 0; mi < 2; mi++)
#pragma unroll
      for (int ni = 0; ni < 4; ni++) acc[mi][ni] = (floatx4){0.f, 0.f, 0.f, 0.f};

#pragma unroll
    for (int kk = 0; kk < 4; kk++) {
      short8 bfrag[4];
#pragma unroll
      for (int ni = 0; ni < 4; ni++)
        bfrag[ni] = *(const short8*)(&ldsB[(ni * 16 + lm) * BPAD + kk * 32 + quad * 8]);
#pragma unroll
      for (int mi = 0; mi < 2; mi++)
#pragma unroll
        for (int ni = 0; ni < 4; ni++)
          acc[mi][ni] = __builtin_amdgcn_mfma_f32_16x16x32_bf16(
              afrag[mi][kk], bfrag[ni], acc[mi][ni], 0, 0, 0);
    }

    if (dg) {
      if (cen) epilogue<true, true>(acc, rs, rowg0, colg0, quad, lm, colsum_ptr, diag_ptr);
      else     epilogue<false, true>(acc, rs, rowg0, colg0, quad, lm, colsum_ptr, diag_ptr);
    } else {
      if (cen) epilogue<true, false>(acc, rs, rowg0, colg0, quad, lm, colsum_ptr, diag_ptr);
      else     epilogue<false, false>(acc, rs, rowg0, colg0, quad, lm, colsum_ptr, diag_ptr);
    }
  }

  // ---- row-sum flush: reduce over lm within quad, one atomic per row ----
#pragma unroll
  for (int mi = 0; mi < 2; mi++) {
#pragma unroll
    for (int r = 0; r < 4; r++) {
      float v = rs[mi][r];
      v += __shfl_xor(v, 1, 64);
      v += __shfl_xor(v, 2, 64);
      v += __shfl_xor(v, 4, 64);
      v += __shfl_xor(v, 8, 64);
      if (lm == 0)
        atomicAdd(&rowsum[task * bsz + rowg0 + mi * 16 + quad * 4 + r], v);
    }
  }

  // ---- last-block loss reduction (decoupled-lookback style) ----
  __threadfence();
  __syncthreads();
  if (tid == 0) {
    int t = __hip_atomic_fetch_add(counter, 1, __ATOMIC_ACQ_REL,
                                   __HIP_MEMORY_SCOPE_AGENT);
    amLast = (t == (int)gridDim.x - 1);
  }
  __syncthreads();
  if (amLast) {
    __threadfence();
    float accv = 0.0f;
    for (int i = tid; i < bsz; i += 256) {
      float s_xx = LDAGENT(rowsum[0 * bsz + i]), d_xx = LDAGENT(diag[0 * bsz + i]);
      float s_yy = LDAGENT(rowsum[1 * bsz + i]), d_yy = LDAGENT(diag[1 * bsz + i]);
      float s_xy = LDAGENT(rowsum[2 * bsz + i]), d_xy = LDAGENT(diag[2 * bsz + i]);
      float s_ax = LDAGENT(rowsum[3 * bsz + i]), d_ax = LDAGENT(diag[3 * bsz + i]);
      float s_ay = LDAGENT(rowsum[4 * bsz + i]), d_ay = LDAGENT(diag[4 * bsz + i]);
      float s_zx = LDAGENT(rowsum[5 * bsz + i]), d_zx = d_ax;
      float s_zy = LDAGENT(rowsum[6 * bsz + i]), d_zy = d_ay;
      float denom = (s_xy - d_xy) + (s_xx - d_xx) + (s_yy - d_yy);
      float tloc = -2.0f * __logf(d_xy / denom);
      tloc -= __logf(d_ax / (s_ax - d_ax));
      tloc -= __logf(d_ay / (s_ay - d_ay));
      tloc -= __logf(d_zx / (s_zx - d_zx));
      tloc -= __logf(d_zy / (s_zy - d_zy));
      accv += tloc;
    }
    red[tid] = accv;
    __syncthreads();
    for (int s = 128; s > 0; s >>= 1) {
      if (tid < s) red[tid] += red[tid + s];
      __syncthreads();
    }
    if (tid == 0) out[0] = red[0] / (float)bsz;
  }
}

// ---------------------------------------------------------------------------
extern "C" void kernel_launch(void* const* d_in, const int* in_sizes, int n_in,
                              void* d_out, int out_size, void* d_ws, size_t ws_size,
                              hipStream_t stream) {
  const float* x = (const float*)d_in[0];
  int rows = in_sizes[0] / D;   // 12288
  int bsz  = rows / 3;          // 4096

  char*  ws       = (char*)d_ws;
  short* xn       = (short*)ws;                        // rows*D bf16
  size_t xn_bytes = (size_t)rows * D * sizeof(short);  // 3 MiB
  float* rowsum   = (float*)(ws + xn_bytes);           // [7][bsz]
  float* dg       = rowsum + 7 * bsz;                  // [5][bsz]
  int*   counter  = (int*)(dg + 5 * bsz);

  normalize_kernel<<<rows / 4, 256, 0, stream>>>(x, xn, rowsum, counter, rows);
  expsim_kernel<<<GRID_EXPSIM, 256, 0, stream>>>(xn, rowsum, dg, counter,
                                                 (float*)d_out, bsz);
}

// Round 4
// 111.464 us; speedup vs baseline: 7.4967x; 3.5528x over previous
//
#include <hip/hip_runtime.h>
#include <hip/hip_bf16.h>

// ---------------------------------------------------------------------------
// LossNet: x (12288,128) fp32 -> scalar loss.  bsz=4096.
// 5 full matrices (zx/zy folded into colsums of xz/yz):
//   task 0 xx, 1 yy, 2 xy, 3 xz (+colsum->s_zx), 4 yz (+colsum->s_zy)
// ALL reductions are exclusive non-atomic stores (R3 post-mortem: 900k
// device-scope atomics at 512+/cacheline serialized -> 347us all-idle).
// ---------------------------------------------------------------------------

typedef __attribute__((ext_vector_type(8))) short short8;   // 8 x bf16
typedef __attribute__((ext_vector_type(4))) float floatx4;  // MFMA acc

#define D      128
#define BM     128    // rows per block
#define BN     64     // cols per j-tile
#define BPAD   136    // LDS row stride in shorts (2-way alias = free)
#define JSPLIT 8      // column splits; 8 j-tiles per block
#define NTPB   8      // tiles per block
// grid: 5 tasks x 32 iblk x 8 jsplit
#define GRID_EXPSIM (5 * 32 * 8)

// ---------------------------------------------------------------------------
// Kernel 1: row-normalize fp32 -> bf16, prescaled by sqrt(10*log2(e)) so the
// MFMA dot product is already the exp2 argument.  Also zeroes out[0].
// ---------------------------------------------------------------------------
__global__ __launch_bounds__(256) void normalize_kernel(
    const float* __restrict__ x, short* __restrict__ xn,
    float* __restrict__ out, int rows) {
  int tid = threadIdx.x;
  if (blockIdx.x == 0 && tid == 0) out[0] = 0.0f;

  int row  = blockIdx.x * 4 + (tid >> 6);
  int lane = tid & 63;
  if (row >= rows) return;
  const float2* xr = (const float2*)(x + (size_t)row * D);
  float2 v = xr[lane];
  float s = v.x * v.x + v.y * v.y;
#pragma unroll
  for (int off = 1; off < 64; off <<= 1) s += __shfl_xor(s, off, 64);
  // sqrt(10 / ln 2): dot(a,b) = 10*log2(e)*cos -> e^(10 cos) = exp2(dot)
  float scale = 3.7982825470322528f / fmaxf(sqrtf(s), 1e-12f);
  __hip_bfloat162 h;
  h.x = __float2bfloat16(v.x * scale);
  h.y = __float2bfloat16(v.y * scale);
  ((__hip_bfloat162*)xn)[(size_t)row * 64 + lane] = h;
}

// ---------------------------------------------------------------------------
// Epilogue: exp2, rowsum partials (registers), optional colsum -> LDS
// accumulator, optional diag store.  C/D layout: col=lm, row=quad*4+reg.
// ---------------------------------------------------------------------------
template <bool COL, bool DIAG>
__device__ __forceinline__ void epilogue(
    const floatx4 (&acc)[2][4], float (&rs)[2][4], int rowg0, int colg0,
    int quad, int lm, int w, int t, float* __restrict__ csLDS,
    float* __restrict__ diag_ptr) {
  float cs[4] = {0.f, 0.f, 0.f, 0.f};
#pragma unroll
  for (int mi = 0; mi < 2; mi++) {
#pragma unroll
    for (int r = 0; r < 4; r++) {
      int rowg = rowg0 + mi * 16 + quad * 4 + r;
      float part = 0.f;
#pragma unroll
      for (int ni = 0; ni < 4; ni++) {
        float e = exp2f(acc[mi][ni][r]);   // acc = 10*log2(e)*cos
        part += e;
        if (COL) cs[ni] += e;
        if (DIAG) {
          if (colg0 + ni * 16 + lm == rowg) diag_ptr[rowg] = e;
        }
      }
      rs[mi][r] += part;
    }
  }
  if (COL) {
    // reduce across quads (rows within wave), accumulate per-wave in LDS
#pragma unroll
    for (int ni = 0; ni < 4; ni++) {
      float v = cs[ni];
      v += __shfl_xor(v, 16, 64);
      v += __shfl_xor(v, 32, 64);
      if (quad == 0) csLDS[w * 512 + t * 64 + ni * 16 + lm] += v;
    }
  }
}

// ---------------------------------------------------------------------------
// Kernel 2: exp-sim.  block = (task, iblk, jsplit); 8 j-tiles of 128x64.
// NOTE: plain __launch_bounds__(256) — min-waves cap spills acc/frags (R2).
// ---------------------------------------------------------------------------
__global__ __launch_bounds__(256) void expsim_kernel(
    const short* __restrict__ xn,
    float* __restrict__ srow,   // [5][JSPLIT][4096] exclusive
    float* __restrict__ scol,   // [2][32][4096] exclusive
    float* __restrict__ diag,   // [5][4096] exclusive
    int bsz) {
  __shared__ short ldsB[BN * BPAD];
  __shared__ float csLDS[4 * 512];   // per-wave colsum accumulators

  int tid = threadIdx.x;
  int bx  = blockIdx.x;
  int task   = bx >> 8;      // 256 blocks per task
  int rem    = bx & 255;
  int iblk   = rem >> 3;
  int jsplit = rem & 7;

  const int aoff_t[5] = {0, 1, 0, 0, 1};
  const int boff_t[5] = {0, 1, 1, 2, 2};
  int arow0     = aoff_t[task] * bsz + iblk * BM;
  int brow_base = boff_t[task] * bsz;
  bool col_en   = (task >= 3);

  int w    = tid >> 6;     // wave: rows w*32..w*32+31
  int lane = tid & 63;
  int quad = lane >> 4;
  int lm   = lane & 15;
  int rowg0 = iblk * BM + w * 32;

  float* diag_ptr = diag + task * bsz;

  if (col_en) {
    for (int i = tid; i < 2048; i += 256) csLDS[i] = 0.0f;
  }

  // ---- A fragments, resident for whole block ----
  short8 afrag[2][4];
#pragma unroll
  for (int mi = 0; mi < 2; mi++) {
    int r = arow0 + w * 32 + mi * 16 + lm;
    const short8* ap = (const short8*)(xn + (size_t)r * D);
#pragma unroll
    for (int kk = 0; kk < 4; kk++) afrag[mi][kk] = ap[kk * 4 + quad];
  }

  float rs[2][4];
#pragma unroll
  for (int mi = 0; mi < 2; mi++)
#pragma unroll
    for (int r = 0; r < 4; r++) rs[mi][r] = 0.0f;

  // ---- 8 j-tiles per block ----
  for (int t = 0; t < NTPB; t++) {
    int jt    = jsplit * NTPB + t;
    int colg0 = jt * BN;
    __syncthreads();
    const short* bsrc = xn + ((size_t)brow_base + colg0) * D;
#pragma unroll
    for (int it = 0; it < 4; it++) {
      int c = it * 256 + tid;
      int br = c >> 4, c16 = c & 15;
      *(short8*)(&ldsB[br * BPAD + c16 * 8]) =
          *(const short8*)(bsrc + (size_t)br * D + c16 * 8);
    }
    __syncthreads();

    floatx4 acc[2][4];
#pragma unroll
    for (int mi = 0; mi < 2; mi++)
#pragma unroll
      for (int ni = 0; ni < 4; ni++) acc[mi][ni] = (floatx4){0.f, 0.f, 0.f, 0.f};

#pragma unroll
    for (int kk = 0; kk < 4; kk++) {
      short8 bfrag[4];
#pragma unroll
      for (int ni = 0; ni < 4; ni++)
        bfrag[ni] = *(const short8*)(&ldsB[(ni * 16 + lm) * BPAD + kk * 32 + quad * 8]);
#pragma unroll
      for (int mi = 0; mi < 2; mi++)
#pragma unroll
        for (int ni = 0; ni < 4; ni++)
          acc[mi][ni] = __builtin_amdgcn_mfma_f32_16x16x32_bf16(
              afrag[mi][kk], bfrag[ni], acc[mi][ni], 0, 0, 0);
    }

    bool isdiag = ((jt >> 1) == iblk);   // tile on the global diagonal
    if (col_en) {
      if (isdiag) epilogue<true, true>(acc, rs, rowg0, colg0, quad, lm, w, t, csLDS, diag_ptr);
      else        epilogue<true, false>(acc, rs, rowg0, colg0, quad, lm, w, t, csLDS, diag_ptr);
    } else {
      if (isdiag) epilogue<false, true>(acc, rs, rowg0, colg0, quad, lm, w, t, csLDS, diag_ptr);
      else        epilogue<false, false>(acc, rs, rowg0, colg0, quad, lm, w, t, csLDS, diag_ptr);
    }
  }

  // ---- row-sum flush: reduce over lm within quad, exclusive store ----
  float* srow_ptr = srow + ((size_t)(task * JSPLIT + jsplit)) * bsz;
#pragma unroll
  for (int mi = 0; mi < 2; mi++) {
#pragma unroll
    for (int r = 0; r < 4; r++) {
      float v = rs[mi][r];
      v += __shfl_xor(v, 1, 64);
      v += __shfl_xor(v, 2, 64);
      v += __shfl_xor(v, 4, 64);
      v += __shfl_xor(v, 8, 64);
      if (lm == 0) srow_ptr[rowg0 + mi * 16 + quad * 4 + r] = v;
    }
  }

  // ---- col-sum flush: cross-wave LDS reduce, exclusive store ----
  if (col_en) {
    __syncthreads();
    float* scol_ptr = scol + ((size_t)((task - 3) * 32 + iblk)) * bsz + jsplit * 512;
    for (int c = tid; c < 512; c += 256) {
      scol_ptr[c] = csLDS[c] + csLDS[512 + c] + csLDS[1024 + c] + csLDS[1536 + c];
    }
  }
}

// ---------------------------------------------------------------------------
// Kernel 3: final loss reduction.  16 blocks x 256 threads, one row each.
// ---------------------------------------------------------------------------
__global__ __launch_bounds__(256) void reduce_kernel(
    const float* __restrict__ srow, const float* __restrict__ scol,
    const float* __restrict__ diag, float* __restrict__ out, int bsz) {
  int tid = threadIdx.x;
  int i   = blockIdx.x * 256 + tid;

  float s[5];
#pragma unroll
  for (int t = 0; t < 5; t++) {
    float a = 0.f;
#pragma unroll
    for (int js = 0; js < JSPLIT; js++) a += srow[(size_t)(t * JSPLIT + js) * bsz + i];
    s[t] = a;
  }
  float s_zx = 0.f, s_zy = 0.f;
#pragma unroll 4
  for (int ib = 0; ib < 32; ib++) {
    s_zx += scol[(size_t)ib * bsz + i];
    s_zy += scol[(size_t)(32 + ib) * bsz + i];
  }
  float d_xx = diag[0 * bsz + i], d_yy = diag[1 * bsz + i];
  float d_xy = diag[2 * bsz + i], d_ax = diag[3 * bsz + i];
  float d_ay = diag[4 * bsz + i];

  float denom = (s[2] - d_xy) + (s[0] - d_xx) + (s[1] - d_yy);
  float tloc = -2.0f * __logf(d_xy / denom);
  tloc -= __logf(d_ax / (s[3] - d_ax));
  tloc -= __logf(d_ay / (s[4] - d_ay));
  tloc -= __logf(d_ax / (s_zx - d_ax));   // d_zx == d_ax
  tloc -= __logf(d_ay / (s_zy - d_ay));   // d_zy == d_ay

  __shared__ float red[256];
  red[tid] = tloc;
  __syncthreads();
  for (int st = 128; st > 0; st >>= 1) {
    if (tid < st) red[tid] += red[tid + st];
    __syncthreads();
  }
  if (tid == 0) atomicAdd(out, red[0] / (float)bsz);
}

// ---------------------------------------------------------------------------
extern "C" void kernel_launch(void* const* d_in, const int* in_sizes, int n_in,
                              void* d_out, int out_size, void* d_ws, size_t ws_size,
                              hipStream_t stream) {
  const float* x = (const float*)d_in[0];
  int rows = in_sizes[0] / D;   // 12288
  int bsz  = rows / 3;          // 4096

  char*  ws       = (char*)d_ws;
  short* xn       = (short*)ws;                        // rows*D bf16: 3 MiB
  size_t xn_bytes = (size_t)rows * D * sizeof(short);
  float* srow     = (float*)(ws + xn_bytes);           // [5][8][4096]: 640 KiB
  float* scol     = srow + 5 * JSPLIT * bsz;           // [2][32][4096]: 1 MiB
  float* diag     = scol + 2 * 32 * bsz;               // [5][4096]: 80 KiB

  normalize_kernel<<<rows / 4, 256, 0, stream>>>(x, xn, (float*)d_out, rows);
  expsim_kernel<<<GRID_EXPSIM, 256, 0, stream>>>(xn, srow, scol, diag, bsz);
  reduce_kernel<<<bsz / 256, 256, 0, stream>>>(srow, scol, diag, (float*)d_out, bsz);
}